// Round 13
// baseline (176.748 us; speedup 1.0000x reference)
//
#include <hip/hip_runtime.h>
#include <hip/hip_bf16.h>
#include <math.h>

#define N     12
#define HID   64
#define STP   68     // fp32 row stride for enc h1/h2 (272 B rows)
#define XST   72     // bf16 row stride (144 B rows; 9-chunk shift per row -> benign conflicts)
#define SLOPE 0.2f
#define ALPHA 0.1f

typedef float v2f __attribute__((ext_vector_type(2)));
typedef float v4f __attribute__((ext_vector_type(4)));
typedef int   i4  __attribute__((ext_vector_type(4)));
typedef short v8s __attribute__((ext_vector_type(8)));

static __device__ __forceinline__ v8s as_v8s(i4 v) {
    union { i4 a; v8s b; } u; u.a = v; return u.b;
}
static __device__ __forceinline__ unsigned short f2bf(float f) {
    __hip_bfloat16 h = __float2bfloat16(f);
    return *(unsigned short*)&h;
}
static __device__ __forceinline__ float bf2f(unsigned short u) {
    return __uint_as_float((unsigned)u << 16);
}

// flat output offsets (float32 elements)
#define OUT0 0
#define OUT1 196608
#define OUT2 245760
#define OUT3 442368
#define OUT4 491520

// ws layout (float offsets):
//   [0,4096)       enc_w2 transposed fp32 (enc stays fp32: latent feeds Gabriel
//                  d2>r2 comparisons -> adjacency must be deterministic)
//   [4096,16384)   6 GAT matrices pre-packed in MFMA B-frag layout, bf16
//   [16384,16640)  labT fp32: labT[c*64+h] = lab_w[h*4+c]
__global__ void prep_kernel(const float* __restrict__ enc_w2,
                            const float* __restrict__ g2_wl, const float* __restrict__ g2_wr,
                            const float* __restrict__ g3_wl, const float* __restrict__ g3_wr,
                            const float* __restrict__ g4_wl, const float* __restrict__ g4_wr,
                            const float* __restrict__ lab_w,
                            float* __restrict__ ws) {
    int t = threadIdx.x;
    int bx = blockIdx.x;
    if (bx < 64) { ws[t*64 + bx] = enc_w2[bx*64 + t]; return; }
    if (bx == 112) {
        #pragma unroll
        for (int c = 0; c < 4; c++) ws[16384 + c*64 + t] = lab_w[t*4 + c];
        return;
    }
    int idx = bx - 64;
    int mat = idx >> 3, rem = idx & 7;
    int kt = rem >> 2, nt = rem & 3;
    const float* src;
    switch (mat) {
        case 0: src = g2_wl; break;
        case 1: src = g2_wr; break;
        case 2: src = g3_wl; break;
        case 3: src = g3_wr; break;
        case 4: src = g4_wl; break;
        default: src = g4_wr; break;
    }
    int quad = t >> 4, col = t & 15;
    int n = nt*16 + col;
    unsigned* dst = (unsigned*)(ws + 4096) + mat*2048 + (kt*4+nt)*256 + t*4;
    #pragma unroll
    for (int jp = 0; jp < 4; jp++) {
        int k0 = kt*32 + quad*8 + 2*jp;
        dst[jp] = (unsigned)f2bf(src[(k0+0)*64 + n]) | ((unsigned)f2bf(src[(k0+1)*64 + n]) << 16);
    }
}

// One graph per 64-lane wave (R7 lesson). DS-pipe-throughput model (R12):
// wall ~= (DS insts/wave ~1000 x ~6cyc x 16 waves)/CU -> minimize DS insts.
// R13 = R12's DS diet WITHOUT the spill triggers:
//  - bf16 xl/xr/x: score divergent reads halved, stage/head LDS traffic halved
//  - gab: ONE fused k-loop for all 3 pair slots (24 broadcasts, not 72) -- no
//    register coordinate arrays (R12's kx/ky/kz[12] spilled: VGPR 84, 24MB WRITE)
//  - batch staged via LDS pool (R11 style)
//  - xl16 aliases enc h1 buffer, xr16 aliases h2 (disjoint, barrier-separated
//    lifetimes): 9152 B LDS -> 16 blocks/CU
// R3/R4: 16-iter fp32 K-loops stay ROLLED. R8: sparse score. R9: MFMA stages.
// R10: softmax fused away (exp/rowsum; diag always present, e=O(1)).
template<bool TW>
__global__ __launch_bounds__(64, 3) void gae_kernel(
    const float* __restrict__ batch,
    const float* __restrict__ enc_w1, const float* __restrict__ enc_b1,
    const float* __restrict__ enc_w2, const float* __restrict__ enc_b2,
    const float* __restrict__ enc_w3, const float* __restrict__ enc_b3,
    const float* __restrict__ g1_wl, const float* __restrict__ g1_wr,
    const float* __restrict__ g1_att, const float* __restrict__ g1_b,
    const float* __restrict__ g2_wl, const float* __restrict__ g2_wr,
    const float* __restrict__ g2_att, const float* __restrict__ g2_b,
    const float* __restrict__ g3_wl, const float* __restrict__ g3_wr,
    const float* __restrict__ g3_att, const float* __restrict__ g3_b,
    const float* __restrict__ g4_wl, const float* __restrict__ g4_wr,
    const float* __restrict__ g4_att, const float* __restrict__ g4_b,
    const float* __restrict__ lab_w, const float* __restrict__ lab_b,
    const float* __restrict__ val_w, const float* __restrict__ val_b,
    const float* __restrict__ skip_w, const float* __restrict__ skip_b,
    const float* __restrict__ wsT,
    float* __restrict__ out)
{
    const int b = blockIdx.x;
    const int t = threadIdx.x;

    __shared__ __align__(16) float bufA[N*STP];   // enc h1; later xl16 (bf16)
    __shared__ __align__(16) float bufB[N*STP];   // enc h2; later xr16 (bf16)
    __shared__ __align__(16) unsigned short xB16[N*XST];
    __shared__ __align__(16) float pool[144];     // batch(60)->lat(36)->exp(e)(144)
    __shared__ __align__(16) float att_s[HID];
    __shared__ __align__(16) unsigned char pairs8[64];

    unsigned short* xl16 = (unsigned short*)bufA;
    unsigned short* xr16 = (unsigned short*)bufB;

    const v2f z2 = {0.f, 0.f};
    const v4f z4 = {0.f, 0.f, 0.f, 0.f};
    const v2f sl2 = {SLOPE, SLOPE};

    // score-pair decomposition (144 pairs, 3 slots of 64/64/16)
    const int p0 = t,        i0 = p0 / N, j0 = p0 - i0*N;
    const int p1 = t + 64,   i1 = p1 / N, j1 = p1 - i1*N;
    const int p2 = (t < 16) ? (t + 128) : 143;
    const int i2 = p2 / N,   j2 = p2 - i2*N;

    // ---- stage batch into pool, emit passthrough outputs 0/1 ----
    if (t < N*5) {
        float v = batch[b*(N*5) + t];
        pool[t] = v;
        int i = t / 5, f = t - i*5;
        if (f < 4) out[OUT0 + (size_t)b*(N*4) + i*4 + f] = v;
        else       out[OUT1 + (size_t)b*N + i] = v;
    }
    __syncthreads();

    // ---- encoder layer 1 ----
    {
        float acc[N];
        float bias = enc_b1[t];
        #pragma unroll
        for (int i=0;i<N;i++) acc[i] = bias;
        #pragma unroll
        for (int f=0; f<5; f++) {
            float w = enc_w1[f*HID + t];
            #pragma unroll
            for (int i=0;i<N;i++) acc[i] = fmaf(pool[i*5+f], w, acc[i]);
        }
        #pragma unroll
        for (int i=0;i<N;i++) bufA[i*STP + t] = fmaxf(acc[i], 0.f);
    }
    __syncthreads();

    // ---- encoder layer 2 (fp32; K-loop ROLLED) ----
    {
        v2f acc[N];
        #pragma unroll
        for (int i=0;i<N;i++) acc[i] = z2;
        const float* w2p = TW ? (wsT + t*HID) : nullptr;
        for (int c=0;c<HID;c+=4) {
            v2f w01, w23;
            if (TW) {
                v4f w4 = *reinterpret_cast<const v4f*>(&w2p[c]);
                w01 = w4.xy; w23 = w4.zw;
            } else {
                w01 = (v2f){enc_w2[(c+0)*HID+t], enc_w2[(c+1)*HID+t]};
                w23 = (v2f){enc_w2[(c+2)*HID+t], enc_w2[(c+3)*HID+t]};
            }
            #pragma unroll
            for (int i=0;i<N;i++) {
                v4f xv = *reinterpret_cast<const v4f*>(&bufA[i*STP + c]);
                acc[i] = __builtin_elementwise_fma(xv.xy, w01, acc[i]);
                acc[i] = __builtin_elementwise_fma(xv.zw, w23, acc[i]);
            }
        }
        float bias = enc_b2[t];
        #pragma unroll
        for (int i=0;i<N;i++) bufB[i*STP + t] = fmaxf(bias + acc[i].x + acc[i].y, 0.f);
    }
    __syncthreads();

    // ---- latent = h2 @ W3 + b3 (lanes 0..35) -> pool[0..35] ----
    if (t < N*3) {
        int i = t / 3, c = t - i*3;
        float acc = enc_b3[c];
        for (int k=0;k<HID;k+=4) {
            v4f xv = *reinterpret_cast<const v4f*>(&bufB[i*STP + k]);
            acc = fmaf(xv.x, enc_w3[(k+0)*3+c], acc);
            acc = fmaf(xv.y, enc_w3[(k+1)*3+c], acc);
            acc = fmaf(xv.z, enc_w3[(k+2)*3+c], acc);
            acc = fmaf(xv.w, enc_w3[(k+3)*3+c], acc);
        }
        pool[t] = acc;
        out[OUT4 + (size_t)b*(N*3) + t] = acc;
    }
    __syncthreads();

    // ---- skip connection -> registers (broadcast pool reads) ----
    float skipv[N];
    {
        float w0 = skip_w[t], w1 = skip_w[HID+t], w2 = skip_w[2*HID+t];
        float bias = skip_b[t];
        #pragma unroll
        for (int i=0;i<N;i++) {
            float v = bias;
            v = fmaf(pool[i*3+0], w0, v);
            v = fmaf(pool[i*3+1], w1, v);
            v = fmaf(pool[i*3+2], w2, v);
            skipv[i] = v;
        }
    }

    // ---- Gabriel adjacency: ONE fused k-loop for the 3 slots ----
    bool g0v, g1v, g2v;
    {
        float a0x = pool[i0*3], a0y = pool[i0*3+1];
        float b0x = pool[j0*3], b0y = pool[j0*3+1];
        float a1x = pool[i1*3], a1y = pool[i1*3+1];
        float b1x = pool[j1*3], b1y = pool[j1*3+1];
        float a2x = pool[i2*3], a2y = pool[i2*3+1];
        float b2x = pool[j2*3], b2y = pool[j2*3+1];
        float m0x = (a0x+b0x)*0.5f, m0y = (a0y+b0y)*0.5f;
        float m1x = (a1x+b1x)*0.5f, m1y = (a1y+b1y)*0.5f;
        float m2x = (a2x+b2x)*0.5f, m2y = (a2y+b2y)*0.5f;
        float d0x = a0x-b0x, d0y = a0y-b0y;
        float d1x = a1x-b1x, d1y = a1y-b1y;
        float d2x = a2x-b2x, d2y = a2y-b2y;
        float r20 = (d0x*d0x + d0y*d0y)*0.25f;
        float r21 = (d1x*d1x + d1y*d1y)*0.25f;
        float r22 = (d2x*d2x + d2y*d2y)*0.25f;
        g0v = (i0 != j0); g1v = (i1 != j1); g2v = (t < 16) && (i2 != j2);
        #pragma unroll
        for (int k=0;k<N;k++) {
            float ekx = pool[k*3], eky = pool[k*3+1];   // broadcast, once for all slots
            float e0x = ekx-m0x, e0y = eky-m0y;
            float e1x = ekx-m1x, e1y = eky-m1y;
            float e2x = ekx-m2x, e2y = eky-m2y;
            g0v = g0v && ((k==i0)||(k==j0)||(e0x*e0x + e0y*e0y > r20));
            g1v = g1v && ((k==i1)||(k==j1)||(e1x*e1x + e1y*e1y > r21));
            g2v = g2v && ((k==i2)||(k==j2)||(e2x*e2x + e2y*e2y > r22));
        }
    }
    unsigned long long gb0 = __ballot(g0v);
    unsigned long long gb1 = __ballot(g1v);
    unsigned long long gb2 = __ballot(g2v);
    auto gbit = [&](int p)->int {
        unsigned long long m = (p < 64) ? gb0 : ((p < 128) ? gb1 : gb2);
        return (int)((m >> (p & 63)) & 1ull);
    };
    const int adjA = gbit(p0) | gbit(j0*N+i0) | (i0 == j0);
    const int adjB = gbit(p1) | gbit(j1*N+i1) | (i1 == j1);
    const int adjC = (t < 16) ? (gbit(p2) | gbit(j2*N+i2) | (i2 == j2)) : 0;

    // ---- compact valid pairs ----
    auto mbcnt64 = [&](unsigned long long m)->int {
        return __builtin_amdgcn_mbcnt_hi((unsigned)(m >> 32),
               __builtin_amdgcn_mbcnt_lo((unsigned)m, 0));
    };
    const unsigned long long am0 = __ballot(adjA != 0);
    const unsigned long long am1 = __ballot(adjB != 0);
    const unsigned long long am2 = __ballot(adjC != 0);
    const int c0  = __popcll(am0);
    const int c01 = c0 + __popcll(am1);
    const int nv  = c01 + __popcll(am2);
    const int idx0 = mbcnt64(am0);
    const int idx1 = c0  + mbcnt64(am1);
    const int idx2 = c01 + mbcnt64(am2);
    if (adjA)               pairs8[idx0] = (unsigned char)p0;
    if (adjB && idx1 < 64)  pairs8[idx1] = (unsigned char)p1;
    if (adjC && idx2 < 64)  pairs8[idx2] = (unsigned char)p2;
    const bool ovB = adjB && (idx1 >= 64);
    const bool ovC = adjC && (idx2 >= 64);
    const int nvc = nv < 64 ? nv : 64;

    // ---- score (bf16 xl/xr; 8 iters x (2 div b128 + 2 bc b128); ROLLED) ----
    auto scoreAt = [&](int i, int j)->float {
        const i4* Lj = reinterpret_cast<const i4*>(xl16 + j*XST);
        const i4* Ri = reinterpret_cast<const i4*>(xr16 + i*XST);
        v2f a2 = z2;
        for (int h=0; h<8; h++) {
            i4 lw = Lj[h];
            i4 rw = Ri[h];
            v4f aa = *reinterpret_cast<const v4f*>(&att_s[h*8]);
            v4f ab = *reinterpret_cast<const v4f*>(&att_s[h*8+4]);
            #pragma unroll
            for (int q=0; q<4; q++) {
                unsigned lu = (unsigned)lw[q], ru = (unsigned)rw[q];
                v2f xl2 = { __uint_as_float(lu << 16), __uint_as_float(lu & 0xffff0000u) };
                v2f xr2 = { __uint_as_float(ru << 16), __uint_as_float(ru & 0xffff0000u) };
                v2f s = xl2 + xr2;
                v2f l = __builtin_elementwise_fma(sl2, __builtin_elementwise_min(s, z2),
                                                  __builtin_elementwise_max(s, z2));
                v2f av = (q==0) ? aa.xy : (q==1) ? aa.zw : (q==2) ? ab.xy : ab.zw;
                a2 = __builtin_elementwise_fma(av, l, a2);
            }
        }
        return a2.x + a2.y;
    };

    // ---- GATv2 core: sparse exp(score) -> sum-normalized aggregate -> bf16 out ----
    auto gat_core = [&](const float* __restrict__ att, const float* __restrict__ gb,
                        unsigned short* __restrict__ out16, int useSkip) {
        att_s[t] = att[t];
        pool[t] = 0.f; pool[t+64] = 0.f;
        if (t < 16) pool[t+128] = 0.f;
        __syncthreads();                    // xl/xr staged + att_s + zeros visible
        if (t < nvc) {
            int p = pairs8[t];
            int i = (p * 171) >> 11;        // p/12 for p<144
            int j = p - i*N;
            pool[p] = __expf(scoreAt(i, j));
        }
        if (nv > 64) {                      // rare overflow (<=4 pairs)
            if (ovB) pool[p1] = __expf(scoreAt(i1, j1));
            if (ovC) pool[p2] = __expf(scoreAt(i2, j2));
        }
        __syncthreads();
        {
            float xj[N];
            #pragma unroll
            for (int j=0;j<N;j++) xj[j] = bf2f(xl16[j*XST + t]);
            v4f X0 = {xj[0], xj[1], xj[2],  xj[3]};
            v4f X1 = {xj[4], xj[5], xj[6],  xj[7]};
            v4f X2 = {xj[8], xj[9], xj[10], xj[11]};
            float bias = gb[t];
            #pragma unroll
            for (int i=0;i<N;i++) {
                const v4f* ep = reinterpret_cast<const v4f*>(&pool[i*N]);
                v4f e0 = ep[0], e1 = ep[1], e2 = ep[2];
                float sum = ((e0.x+e0.y)+(e0.z+e0.w))
                          + ((e1.x+e1.y)+(e1.z+e1.w))
                          + ((e2.x+e2.y)+(e2.z+e2.w));
                v4f acc = __builtin_elementwise_fma(e0, X0,
                          __builtin_elementwise_fma(e1, X1, e2*X2));
                float r = bias + ((acc.x + acc.y) + (acc.z + acc.w)) / sum;
                if (useSkip) r = fmaf(ALPHA, skipv[i], r);
                out16[i*XST + t] = f2bf(fmaxf(r, 0.f));
            }
        }
        __syncthreads();
    };

    // ---- MFMA stage: xl16/xr16 <- xB16 @ {wl, wr}; A-frag = one 16B ds_read ----
    auto stage_mfma = [&](int matL) {
        const int m = t & 15, quad = t >> 4;
        const int mc = (m < N) ? m : 0;     // rows 12..15 discarded anyway
        i4 aF0 = *reinterpret_cast<const i4*>(&xB16[mc*XST + quad*8]);
        i4 aF1 = *reinterpret_cast<const i4*>(&xB16[mc*XST + 32 + quad*8]);
        const i4* bbase = reinterpret_cast<const i4*>(wsT + 4096);
        #pragma unroll
        for (int mm=0; mm<2; mm++) {
            const i4* bp = bbase + (matL + mm)*512;
            v4f acc[4] = {z4, z4, z4, z4};
            #pragma unroll
            for (int nt=0; nt<4; nt++) {
                i4 b0 = bp[(0*4+nt)*64 + t];
                i4 b1 = bp[(1*4+nt)*64 + t];
                acc[nt] = __builtin_amdgcn_mfma_f32_16x16x32_bf16(as_v8s(aF0), as_v8s(b0), acc[nt], 0, 0, 0);
                acc[nt] = __builtin_amdgcn_mfma_f32_16x16x32_bf16(as_v8s(aF1), as_v8s(b1), acc[nt], 0, 0, 0);
            }
            unsigned short* dst = (mm == 0) ? xl16 : xr16;
            if (quad < 3) {
                #pragma unroll
                for (int nt=0; nt<4; nt++) {
                    #pragma unroll
                    for (int r=0; r<4; r++)
                        dst[(quad*4+r)*XST + nt*16 + m] = f2bf(acc[nt][r]);
                }
            }
        }
    };

    // ---- fallback stage (TW=false): VALU, global fp32 weights, bf16 x ----
    auto stage = [&](const float* __restrict__ wl, const float* __restrict__ wr) {
        v2f al[N], ar[N];
        #pragma unroll
        for (int i=0;i<N;i++) { al[i] = z2; ar[i] = z2; }
        for (int c=0;c<HID;c+=2) {
            v2f wlv = (v2f){wl[(c+0)*HID+t], wl[(c+1)*HID+t]};
            v2f wrv = (v2f){wr[(c+0)*HID+t], wr[(c+1)*HID+t]};
            #pragma unroll
            for (int i=0;i<N;i++) {
                unsigned xu = *(const unsigned*)&xB16[i*XST + c];
                v2f xv = { __uint_as_float(xu << 16), __uint_as_float(xu & 0xffff0000u) };
                al[i] = __builtin_elementwise_fma(xv, wlv, al[i]);
                ar[i] = __builtin_elementwise_fma(xv, wrv, ar[i]);
            }
        }
        #pragma unroll
        for (int i=0;i<N;i++) {
            xl16[i*XST + t] = f2bf(al[i].x + al[i].y);
            xr16[i*XST + t] = f2bf(ar[i].x + ar[i].y);
        }
    };

    // ---- GAT layer 1 (cin = 1; x0 = lat[:,2] via broadcast pool reads) ----
    {
        float wlv = g1_wl[t], wrv = g1_wr[t];
        #pragma unroll
        for (int i=0;i<N;i++) {
            float v = pool[i*3+2];
            xl16[i*XST + t] = f2bf(v * wlv);
            xr16[i*XST + t] = f2bf(v * wrv);
        }
    }
    gat_core(g1_att, g1_b, xB16, 0);        // x1 -> xB16

    // ---- GAT layer 2 ----
    if (TW) stage_mfma(0); else stage(g2_wl, g2_wr);
    gat_core(g2_att, g2_b, xB16, 0);        // x2 -> xB16 (persists for g3,g4)

    // ---- GAT layer 3 ----
    if (TW) stage_mfma(2); else stage(g3_wl, g3_wr);
    gat_core(g3_att, g3_b, xr16, 1);        // x3 -> xr16

    // ---- logits head: x3 @ lab_w + lab_b (reads xr16 before g4 stage overwrites;
    //      single-wave block: same-array dependence keeps order) ----
    if (t < N*4) {
        int i = t >> 2, c = t & 3;
        float acc = lab_b[c];
        const unsigned* xp = (const unsigned*)&xr16[i*XST];
        if (TW) {
            const float* lwT = wsT + 16384 + c*HID;
            for (int h=0;h<HID;h+=2) {
                unsigned xu = xp[h>>1];
                acc = fmaf(__uint_as_float(xu << 16), lwT[h], acc);
                acc = fmaf(__uint_as_float(xu & 0xffff0000u), lwT[h+1], acc);
            }
        } else {
            for (int h=0;h<HID;h+=2) {
                unsigned xu = xp[h>>1];
                acc = fmaf(__uint_as_float(xu << 16), lab_w[(h+0)*4+c], acc);
                acc = fmaf(__uint_as_float(xu & 0xffff0000u), lab_w[(h+1)*4+c], acc);
            }
        }
        out[OUT2 + (size_t)b*(N*4) + t] = acc;
    }
    __syncthreads();   // ensure head reads complete before stage4 overwrites xr16

    // ---- GAT layer 4 (reads x2 from xB16) ----
    if (TW) stage_mfma(4); else stage(g4_wl, g4_wr);
    gat_core(g4_att, g4_b, xr16, 1);        // x4 -> xr16

    // ---- values head ----
    if (t < N) {
        float acc = val_b[0];
        const unsigned* xp = (const unsigned*)&xr16[t*XST];
        for (int h=0;h<HID;h+=2) {
            unsigned xu = xp[h>>1];
            acc = fmaf(__uint_as_float(xu << 16), val_w[h], acc);
            acc = fmaf(__uint_as_float(xu & 0xffff0000u), val_w[h+1], acc);
        }
        out[OUT3 + (size_t)b*N + t] = acc;
    }
}

extern "C" void kernel_launch(void* const* d_in, const int* in_sizes, int n_in,
                              void* d_out, int out_size, void* d_ws, size_t ws_size,
                              hipStream_t stream) {
    (void)in_sizes; (void)n_in; (void)out_size;
    const bool useT = (ws_size >= (16384 + 256)*sizeof(float));
    if (useT) {
        prep_kernel<<<dim3(113), dim3(64), 0, stream>>>(
            (const float*)d_in[3],
            (const float*)d_in[11], (const float*)d_in[12],
            (const float*)d_in[15], (const float*)d_in[16],
            (const float*)d_in[19], (const float*)d_in[20],
            (const float*)d_in[23],
            (float*)d_ws);
        gae_kernel<true><<<dim3(4096), dim3(64), 0, stream>>>(
            (const float*)d_in[0],
            (const float*)d_in[1],  (const float*)d_in[2],
            (const float*)d_in[3],  (const float*)d_in[4],
            (const float*)d_in[5],  (const float*)d_in[6],
            (const float*)d_in[7],  (const float*)d_in[8],  (const float*)d_in[9],  (const float*)d_in[10],
            (const float*)d_in[11], (const float*)d_in[12], (const float*)d_in[13], (const float*)d_in[14],
            (const float*)d_in[15], (const float*)d_in[16], (const float*)d_in[17], (const float*)d_in[18],
            (const float*)d_in[19], (const float*)d_in[20], (const float*)d_in[21], (const float*)d_in[22],
            (const float*)d_in[23], (const float*)d_in[24],
            (const float*)d_in[25], (const float*)d_in[26],
            (const float*)d_in[27], (const float*)d_in[28],
            (const float*)d_ws,
            (float*)d_out);
    } else {
        gae_kernel<false><<<dim3(4096), dim3(64), 0, stream>>>(
            (const float*)d_in[0],
            (const float*)d_in[1],  (const float*)d_in[2],
            (const float*)d_in[3],  (const float*)d_in[4],
            (const float*)d_in[5],  (const float*)d_in[6],
            (const float*)d_in[7],  (const float*)d_in[8],  (const float*)d_in[9],  (const float*)d_in[10],
            (const float*)d_in[11], (const float*)d_in[12], (const float*)d_in[13], (const float*)d_in[14],
            (const float*)d_in[15], (const float*)d_in[16], (const float*)d_in[17], (const float*)d_in[18],
            (const float*)d_in[19], (const float*)d_in[20], (const float*)d_in[21], (const float*)d_in[22],
            (const float*)d_in[23], (const float*)d_in[24],
            (const float*)d_in[25], (const float*)d_in[26],
            (const float*)d_in[27], (const float*)d_in[28],
            nullptr,
            (float*)d_out);
    }
}